// Round 4
// baseline (716.464 us; speedup 1.0000x reference)
//
#include <hip/hip_runtime.h>
#include <hip/hip_cooperative_groups.h>
#include <stdint.h>

// Problem constants (from reference)
#define BATCH   2048
#define IN_BITS 4096
#define N_IN    2048
#define N_ST    1024
#define N_OUT   1024
#define KBITS   14
#define MW      512   // 2^14 bits / 32 = words per packed mem row
#define SROW    96    // s_inp/o_inp packed row words: 3072 bits

// float4 counts per mem table
#define IM4 8388608   // N_IN * 16384 / 4
#define SM4 4194304
#define OM4 4194304
#define GS  524288    // fallback grid-stride: 2048 blocks * 256 threads
#define FTH 262144    // fused grid: 1024 blocks * 256 threads

typedef float f32x4 __attribute__((ext_vector_type(4)));
typedef int   i32x4 __attribute__((ext_vector_type(4)));

namespace cg = cooperative_groups;

// ===========================================================================
// FUSED cooperative kernel (R4). Rationale: R2/R3 showed total time nearly
// invariant to big per-kernel restructures while first-principles throughput
// math says the work is ~100 us — the gap is inter-kernel launch/drain
// boundaries + cold-table refetch + profiler blindness (fills crowd top-5).
// One kernel, 4 phases, grid.sync between them. 1024 blocks x 256 thr =
// exactly 4 blocks/CU; LDS 32 KB (max 5/CU -> co-residency margin).
// ===========================================================================

// Ballot-layout pack helper: wave loads 256 consecutive floats/ints, forms 4
// ballots, lanes 0..7 store 8 u32 words. Consumer remap for bit address a:
//   word = ((a>>5)&~7) | ((a&3)<<1) | ((a>>7)&1);  shift = (a>>2)&31
__device__ __forceinline__ void pack4f(const float* __restrict__ s,
                                       uint32_t* __restrict__ d, long i, int lane) {
    f32x4 v = __builtin_nontemporal_load((const f32x4*)s + i);
    unsigned long long b0 = __ballot(v[0] == 1.0f);
    unsigned long long b1 = __ballot(v[1] == 1.0f);
    unsigned long long b2 = __ballot(v[2] == 1.0f);
    unsigned long long b3 = __ballot(v[3] == 1.0f);
    if (lane < 8) {
        unsigned long long bj = (lane & 4) ? ((lane & 2) ? b3 : b2)
                                           : ((lane & 2) ? b1 : b0);
        uint32_t w = (lane & 1) ? (uint32_t)(bj >> 32) : (uint32_t)bj;
        d[((i >> 6) << 3) + lane] = w;
    }
}
__device__ __forceinline__ void pack4i(const int* __restrict__ s,
                                       uint32_t* __restrict__ d, long i, int lane) {
    i32x4 v = __builtin_nontemporal_load((const i32x4*)s + i);
    unsigned long long b0 = __ballot(v[0] == 1);
    unsigned long long b1 = __ballot(v[1] == 1);
    unsigned long long b2 = __ballot(v[2] == 1);
    unsigned long long b3 = __ballot(v[3] == 1);
    if (lane < 8) {
        unsigned long long bj = (lane & 4) ? ((lane & 2) ? b3 : b2)
                                           : ((lane & 2) ? b1 : b0);
        uint32_t w = (lane & 1) ? (uint32_t)(bj >> 32) : (uint32_t)bj;
        d[((i >> 6) << 3) + lane] = w;
    }
}

// RAM phase: lane = batch (64/block), wave = neuron group. conn/wd/sh are
// wave-uniform (scalar); LDS reads XOR-swizzled -> 2 lanes/bank (free, m136);
// mem gather touches ONE 2KB row per wave-instr. ng in LOW bits of bid ->
// all batch-groups of a neuron slice land on one XCD -> its L2 holds only
// that slice's mem rows (~0.5 MB).
// MODE 0: 16 bits/lane -> ushort into dst0+dst1 words 0..63 (linear order)
// MODE 1: 8 bits/lane  -> uchar into dst0 words 64..95
// MODE 2: 8 bits/lane  -> 8 floats (2x float4, contiguous per thread)
template <int SRCW, int NPB, int MODE>
__device__ __forceinline__ void ram_phase(const uint32_t* __restrict__ src,
                                          const int* __restrict__ conn,
                                          const uint32_t* __restrict__ memp,
                                          uint32_t* __restrict__ dst0,
                                          uint32_t* __restrict__ dst1,
                                          float* __restrict__ fout,
                                          uint32_t* lds) {
    const int tid = threadIdx.x;
    const int bid = blockIdx.x;
    const int ng = bid & 31;   // neuron group (XCD-affine: ng%8 == bid%8)
    const int bg = bid >> 5;   // batch group
    const int b0 = bg * 64;

    // Stage 64 batch rows. Row r padded to 128 words; word w stored at
    // (w ^ (r&31)) -> read bank = (wd ^ (lane&31)) & 31 = free 2-way.
    {
        const uint32_t* g = src + (long)b0 * SRCW;
        for (int i = tid; i < 64 * SRCW; i += 256) {
            int r = i / SRCW;
            int w = i - r * SRCW;
            lds[r * 128 + (w ^ (r & 31))] = g[i];
        }
    }
    __syncthreads();

    const int lane = tid & 63;
    const int lx = lane & 31;
    const int wave = __builtin_amdgcn_readfirstlane(tid >> 6);
    constexpr int NPW = NPB / 4;            // neurons per wave
    const int n0 = ng * NPB + wave * NPW;
    const long b = b0 + lane;
    const uint32_t* row = lds + lane * 128;

    uint32_t acc = 0;
#pragma unroll 4
    for (int j = 0; j < NPW; ++j) {
        const int n = n0 + j;
        const int* cp = conn + n * KBITS;   // wave-uniform -> scalar loads
        uint32_t addr = 0;
#pragma unroll
        for (int k = 0; k < KBITS; ++k) {
            int idx = cp[k];
            int wd, sh;
            if (SRCW == 128) {              // bits1 is ballot layout
                wd = ((idx >> 5) & ~7) | ((idx & 3) << 1) | ((idx >> 7) & 1);
                sh = (idx >> 2) & 31;
            } else {                        // SROW buffers are linear layout
                wd = idx >> 5;
                sh = idx & 31;
            }
            addr = (addr << 1) | ((row[wd ^ lx] >> sh) & 1u);
        }
        // mem tables are ballot layout: remap bit address -> (word, shift)
        uint32_t mw = ((addr >> 5) & ~7u) | ((addr & 3u) << 1) | ((addr >> 7) & 1u);
        uint32_t bit = (memp[(long)n * MW + mw] >> ((addr >> 2) & 31u)) & 1u;
        acc |= bit << j;
    }
    if (MODE == 0) {
        const int woff = n0 >> 5;           // linear bit order
        const int half = (n0 >> 4) & 1;
        ((ushort*)(dst0 + b * SROW + woff))[half] = (ushort)acc;
        ((ushort*)(dst1 + b * SROW + woff))[half] = (ushort)acc;
    } else if (MODE == 1) {
        ((unsigned char*)(dst0 + b * SROW + 64))[n0 >> 3] = (unsigned char)acc;
    } else {
        float* op = fout + b * N_OUT + n0;
        f32x4 fa, fb;
#pragma unroll
        for (int q = 0; q < 4; ++q) {
            fa[q] = (float)((acc >> q) & 1u);
            fb[q] = (float)((acc >> (q + 4)) & 1u);
        }
        *(f32x4*)op = fa;
        *((f32x4*)op + 1) = fb;
    }
}

__global__ __launch_bounds__(256, 4) void fused_all(
    const int* __restrict__ input_bits, const int* __restrict__ state_bits,
    const int* __restrict__ in_conn, const float* __restrict__ in_mem,
    const int* __restrict__ st_conn, const float* __restrict__ st_mem,
    const int* __restrict__ out_conn, const float* __restrict__ out_mem,
    float* __restrict__ out,
    uint32_t* __restrict__ bits1, uint32_t* __restrict__ buf_s,
    uint32_t* __restrict__ buf_o, uint32_t* __restrict__ im_p,
    uint32_t* __restrict__ sm_p, uint32_t* __restrict__ om_p) {
    __shared__ uint32_t lds[64 * 128];      // 32 KB, reused across phases
    const int t = blockIdx.x * 256 + threadIdx.x;   // [0, FTH)
    const int lane = threadIdx.x & 63;

    // ---- Phase A: pack everything (independent streams overlap here) ----
#pragma unroll 4
    for (int c = 0; c < 32; ++c) pack4f(in_mem, im_p, (long)c * FTH + t, lane);
#pragma unroll 4
    for (int c = 0; c < 16; ++c) pack4f(st_mem, sm_p, (long)c * FTH + t, lane);
#pragma unroll 4
    for (int c = 0; c < 16; ++c) pack4f(out_mem, om_p, (long)c * FTH + t, lane);
#pragma unroll
    for (int c = 0; c < 8; ++c)  pack4i(input_bits, bits1, (long)c * FTH + t, lane);
    // state -> buf_s words 64..95 (LINEAR layout, matches SROW consumers)
#pragma unroll
    for (int c = 0; c < 2; ++c) {
        long i = (long)c * FTH + t;         // int4 index, 524288 total
        i32x4 v = __builtin_nontemporal_load((const i32x4*)state_bits + i);
        uint32_t nib = (uint32_t)(v[0] == 1) | ((uint32_t)(v[1] == 1) << 1) |
                       ((uint32_t)(v[2] == 1) << 2) | ((uint32_t)(v[3] == 1) << 3);
        uint32_t w = nib << (4 * (lane & 7));
        w |= __shfl_xor(w, 1, 64);
        w |= __shfl_xor(w, 2, 64);
        w |= __shfl_xor(w, 4, 64);
        if ((lane & 7) == 0) {
            long g = i >> 3;
            long r = g >> 5;
            int  cc = (int)(g & 31);
            buf_s[r * SROW + 64 + cc] = w;
        }
    }
    cg::this_grid().sync();

    // ---- Phase B: layer 1 (h_in -> buf_s & buf_o words 0..63) ----
    ram_phase<128, 64, 0>(bits1, in_conn, im_p, buf_s, buf_o, nullptr, lds);
    cg::this_grid().sync();

    // ---- Phase C: layer 2 (s_out -> buf_o words 64..95) ----
    ram_phase<SROW, 32, 1>(buf_s, st_conn, sm_p, buf_o, nullptr, nullptr, lds);
    cg::this_grid().sync();

    // ---- Phase D: layer 3 (floats) ----
    ram_phase<SROW, 32, 2>(buf_o, out_conn, om_p, nullptr, nullptr, out, lds);
}

// ===========================================================================
// Fallback path (R3 kernels, proven correct) if cooperative launch fails.
// ===========================================================================
__global__ __launch_bounds__(256) void pack_mem_all(const float* __restrict__ im,
                                                    const float* __restrict__ sm,
                                                    const float* __restrict__ om,
                                                    uint32_t* __restrict__ im_p,
                                                    uint32_t* __restrict__ sm_p,
                                                    uint32_t* __restrict__ om_p) {
    const int t = blockIdx.x * 256 + threadIdx.x;
    const int lane = threadIdx.x & 63;
#pragma unroll
    for (int c = 0; c < 32; ++c) {
        const float* s; uint32_t* d; int cl;
        if (c < 16)      { s = im; d = im_p; cl = c; }
        else if (c < 24) { s = sm; d = sm_p; cl = c - 16; }
        else             { s = om; d = om_p; cl = c - 24; }
        pack4f(s, d, (long)cl * GS + t, lane);
    }
}
__global__ __launch_bounds__(256) void pack_input(const int* __restrict__ src,
                                                  uint32_t* __restrict__ dst) {
    const int t = blockIdx.x * 256 + threadIdx.x;
    const int lane = threadIdx.x & 63;
#pragma unroll
    for (int c = 0; c < 4; ++c) pack4i(src, dst, (long)c * GS + t, lane);
}
__global__ __launch_bounds__(256) void pack_state(const int4* __restrict__ src,
                                                  uint32_t* __restrict__ dst) {
    int t = blockIdx.x * 256 + threadIdx.x;
    int4 v = src[t];
    uint32_t nib = (uint32_t)(v.x == 1) | ((uint32_t)(v.y == 1) << 1) |
                   ((uint32_t)(v.z == 1) << 2) | ((uint32_t)(v.w == 1) << 3);
    int lane = threadIdx.x & 63;
    uint32_t w = nib << (4 * (lane & 7));
    w |= __shfl_xor(w, 1, 64);
    w |= __shfl_xor(w, 2, 64);
    w |= __shfl_xor(w, 4, 64);
    if ((lane & 7) == 0) {
        int g = t >> 3;
        dst[(long)(g >> 5) * SROW + 64 + (g & 31)] = w;
    }
}
template <int SRCW, int MODE>
__global__ __launch_bounds__(256) void ram_layer_t(const uint32_t* __restrict__ src,
                                                   const int* __restrict__ conn,
                                                   const uint32_t* __restrict__ memp,
                                                   uint32_t* __restrict__ dst0,
                                                   uint32_t* __restrict__ dst1,
                                                   float* __restrict__ fout) {
    constexpr int LSTR = SRCW + 1;
    __shared__ uint32_t lds[64 * LSTR];
    const int tid = threadIdx.x;
    const int b0 = blockIdx.y * 64;
    {
        const uint4* g = (const uint4*)(src + (long)b0 * SRCW);
        constexpr int NQ = 64 * SRCW / 4;
#pragma unroll
        for (int i = tid; i < NQ; i += 256) {
            uint4 v = g[i];
            int r = i / (SRCW / 4);
            int w = (i - r * (SRCW / 4)) * 4;
            uint32_t* p = &lds[r * LSTR + w];
            p[0] = v.x; p[1] = v.y; p[2] = v.z; p[3] = v.w;
        }
    }
    __syncthreads();
    const int lane = tid & 63;
    const int wave = __builtin_amdgcn_readfirstlane(tid >> 6);
    const int nw0 = blockIdx.x * 64 + wave * 16;
    const long b = b0 + lane;
    const uint32_t* row = lds + lane * LSTR;
    uint32_t acc = 0;
#pragma unroll 2
    for (int j = 0; j < 16; ++j) {
        const int n = nw0 + j;
        const int* cp = conn + n * KBITS;
        uint32_t addr = 0;
#pragma unroll
        for (int k = 0; k < KBITS; ++k) {
            int idx = cp[k];
            int wd, sh;
            if (SRCW == 128) {
                wd = ((idx >> 5) & ~7) | ((idx & 3) << 1) | ((idx >> 7) & 1);
                sh = (idx >> 2) & 31;
            } else {
                wd = idx >> 5;
                sh = idx & 31;
            }
            addr = (addr << 1) | ((row[wd] >> sh) & 1u);
        }
        uint32_t mw = ((addr >> 5) & ~7u) | ((addr & 3u) << 1) | ((addr >> 7) & 1u);
        uint32_t bit = (memp[(long)n * MW + mw] >> ((addr >> 2) & 31u)) & 1u;
        if (MODE == 2) fout[b * N_OUT + n] = (float)bit;
        else           acc |= bit << j;
    }
    if (MODE != 2) {
        const int woff = (MODE == 0 ? 0 : 64) + (nw0 >> 5);
        const int half = (nw0 >> 4) & 1;
        ((ushort*)(dst0 + b * SROW + woff))[half] = (ushort)acc;
        if (MODE == 0)
            ((ushort*)(dst1 + b * SROW + woff))[half] = (ushort)acc;
    }
}

// ---------------------------------------------------------------------------
extern "C" void kernel_launch(void* const* d_in, const int* in_sizes, int n_in,
                              void* d_out, int out_size, void* d_ws, size_t ws_size,
                              hipStream_t stream) {
    const int*   input_bits = (const int*)d_in[0];
    const int*   state_bits = (const int*)d_in[1];
    const int*   in_conn    = (const int*)d_in[2];
    const float* in_mem     = (const float*)d_in[3];
    const int*   st_conn    = (const int*)d_in[4];
    const float* st_mem     = (const float*)d_in[5];
    const int*   out_conn   = (const int*)d_in[6];
    const float* out_mem    = (const float*)d_in[7];
    float*       out        = (float*)d_out;

    char* ws = (char*)d_ws;
    uint32_t* bits1 = (uint32_t*)(ws);
    uint32_t* buf_s = (uint32_t*)(ws + 1048576);
    uint32_t* buf_o = (uint32_t*)(ws + 1048576 + 786432);
    uint32_t* im_p  = (uint32_t*)(ws + 1048576 + 2 * 786432);
    uint32_t* sm_p  = (uint32_t*)(ws + 1048576 + 2 * 786432 + 4194304);
    uint32_t* om_p  = (uint32_t*)(ws + 1048576 + 2 * 786432 + 4194304 + 2097152);

    void* kargs[] = {
        (void*)&input_bits, (void*)&state_bits, (void*)&in_conn, (void*)&in_mem,
        (void*)&st_conn, (void*)&st_mem, (void*)&out_conn, (void*)&out_mem,
        (void*)&out, (void*)&bits1, (void*)&buf_s, (void*)&buf_o,
        (void*)&im_p, (void*)&sm_p, (void*)&om_p};
    hipError_t err = hipLaunchCooperativeKernel((const void*)fused_all,
                                                dim3(1024), dim3(256),
                                                kargs, 0, stream);
    if (err != hipSuccess) {
        // Fallback: proven 6-kernel path (R3).
        pack_input<<<2048, 256, 0, stream>>>(input_bits, bits1);
        pack_state<<<(BATCH * N_ST / 4) / 256, 256, 0, stream>>>((const int4*)state_bits, buf_s);
        pack_mem_all<<<2048, 256, 0, stream>>>(in_mem, st_mem, out_mem, im_p, sm_p, om_p);
        ram_layer_t<128, 0><<<dim3(N_IN / 64, BATCH / 64), 256, 0, stream>>>(
            bits1, in_conn, im_p, buf_s, buf_o, nullptr);
        ram_layer_t<SROW, 1><<<dim3(N_ST / 64, BATCH / 64), 256, 0, stream>>>(
            buf_s, st_conn, sm_p, buf_o, nullptr, nullptr);
        ram_layer_t<SROW, 2><<<dim3(N_OUT / 64, BATCH / 64), 256, 0, stream>>>(
            buf_o, out_conn, om_p, nullptr, nullptr, out);
    }
}

// Round 5
// 374.500 us; speedup vs baseline: 1.9131x; 1.9131x over previous
//
#include <hip/hip_runtime.h>
#include <stdint.h>

// Problem constants (from reference)
#define BATCH   2048
#define IN_BITS 4096
#define N_IN    2048
#define N_ST    1024
#define N_OUT   1024
#define KBITS   14
#define MW      512   // 2^14 bits / 32 = words per packed mem row
#define SROW    96    // s_inp/o_inp packed row words: 3072 bits

#define GS  524288    // grid: 2048 blocks * 256 threads

typedef float f32x4 __attribute__((ext_vector_type(4)));
typedef int   i32x4 __attribute__((ext_vector_type(4)));

// ---------------------------------------------------------------------------
// Ballot-layout emit: from a loaded float4/int4, form 4 ballots, lanes 0..7
// store the chunk's 8 u32 words. Consumer remap for bit address a:
//   word = ((a>>5)&~7) | ((a&3)<<1) | ((a>>7)&1);  shift = (a>>2)&31
__device__ __forceinline__ void emit1f(uint32_t* __restrict__ d, long i,
                                       int lane, f32x4 v) {
    unsigned long long b0 = __ballot(v[0] == 1.0f);
    unsigned long long b1 = __ballot(v[1] == 1.0f);
    unsigned long long b2 = __ballot(v[2] == 1.0f);
    unsigned long long b3 = __ballot(v[3] == 1.0f);
    if (lane < 8) {
        unsigned long long bj = (lane & 4) ? ((lane & 2) ? b3 : b2)
                                           : ((lane & 2) ? b1 : b0);
        uint32_t w = (lane & 1) ? (uint32_t)(bj >> 32) : (uint32_t)bj;
        d[((i >> 6) << 3) + lane] = w;
    }
}
__device__ __forceinline__ void emit1i(uint32_t* __restrict__ d, long i,
                                       int lane, i32x4 v) {
    unsigned long long b0 = __ballot(v[0] == 1);
    unsigned long long b1 = __ballot(v[1] == 1);
    unsigned long long b2 = __ballot(v[2] == 1);
    unsigned long long b3 = __ballot(v[3] == 1);
    if (lane < 8) {
        unsigned long long bj = (lane & 4) ? ((lane & 2) ? b3 : b2)
                                           : ((lane & 2) ? b1 : b0);
        uint32_t w = (lane & 1) ? (uint32_t)(bj >> 32) : (uint32_t)bj;
        d[((i >> 6) << 3) + lane] = w;
    }
}

// ---------------------------------------------------------------------------
// ONE pack kernel for everything. R4 post-mortem: the old pack had
// VGPR_Count=8 -> the compiler serialized loads (1 x 16B in flight per wave)
// -> stuck at ~3 TB/s regardless of grid shape. Here loads are EXPLICITLY
// batched 8-deep into named register arrays and double-buffered (load batch
// B while emitting batch A), forcing >=16 loads in flight per wave. Loads
// are cached (not NT): ~half the 256 MB of tables survives in L3 across
// iterations (R0: FETCH 131 MB < 256 MB read).
// Per thread: 32 mem chunks + 4 input chunks + 1 state chunk (uniform work).
__global__ __launch_bounds__(256) void pack_all(
    const float* __restrict__ im, const float* __restrict__ sm,
    const float* __restrict__ om, const int* __restrict__ ib,
    const int* __restrict__ sb,
    uint32_t* __restrict__ im_p, uint32_t* __restrict__ sm_p,
    uint32_t* __restrict__ om_p, uint32_t* __restrict__ bits1,
    uint32_t* __restrict__ buf_s) {
    const long t = blockIdx.x * 256 + threadIdx.x;   // [0, GS)
    const int lane = threadIdx.x & 63;

    f32x4 va[8], vb[8];
    // batch 0: im chunks 0..7
#pragma unroll
    for (int u = 0; u < 8; ++u) va[u] = ((const f32x4*)im)[(long)u * GS + t];
    // batch 1: im chunks 8..15 (in flight while emitting batch 0)
#pragma unroll
    for (int u = 0; u < 8; ++u) vb[u] = ((const f32x4*)im)[(long)(u + 8) * GS + t];
#pragma unroll
    for (int u = 0; u < 8; ++u) emit1f(im_p, (long)u * GS + t, lane, va[u]);
    // batch 2: sm chunks 0..7
#pragma unroll
    for (int u = 0; u < 8; ++u) va[u] = ((const f32x4*)sm)[(long)u * GS + t];
#pragma unroll
    for (int u = 0; u < 8; ++u) emit1f(im_p, (long)(u + 8) * GS + t, lane, vb[u]);
    // batch 3: om chunks 0..7
#pragma unroll
    for (int u = 0; u < 8; ++u) vb[u] = ((const f32x4*)om)[(long)u * GS + t];
#pragma unroll
    for (int u = 0; u < 8; ++u) emit1f(sm_p, (long)u * GS + t, lane, va[u]);
    // input batch: 4 chunks
    i32x4 wi[4];
#pragma unroll
    for (int u = 0; u < 4; ++u) wi[u] = ((const i32x4*)ib)[(long)u * GS + t];
    i32x4 wst = ((const i32x4*)sb)[t];
#pragma unroll
    for (int u = 0; u < 8; ++u) emit1f(om_p, (long)u * GS + t, lane, vb[u]);
#pragma unroll
    for (int u = 0; u < 4; ++u) emit1i(bits1, (long)u * GS + t, lane, wi[u]);
    // state -> buf_s words 64..95, LINEAR layout (matches SROW consumers)
    {
        uint32_t nib = (uint32_t)(wst[0] == 1) | ((uint32_t)(wst[1] == 1) << 1) |
                       ((uint32_t)(wst[2] == 1) << 2) | ((uint32_t)(wst[3] == 1) << 3);
        uint32_t w = nib << (4 * (lane & 7));
        w |= __shfl_xor(w, 1, 64);
        w |= __shfl_xor(w, 2, 64);
        w |= __shfl_xor(w, 4, 64);
        if ((lane & 7) == 0) {
            long g = t >> 3;          // global word index
            buf_s[(g >> 5) * SROW + 64 + (int)(g & 31)] = w;
        }
    }
}

// ---------------------------------------------------------------------------
// TRANSPOSED RAM layer (R3, proven; ~25-30 us total for all three = near its
// LDS-pipe roofline). lane = batch (64/block), wave = 16-neuron group.
// conn/wd/sh wave-uniform (scalar loads); LDS reads via odd stride ->
// 2 lanes/bank (free); mem gather touches one 2KB row per wave-instr;
// gridX = neuron group -> XCD-affine (x%8) so each XCD's L2 holds 1/8 of
// the packed table.
// MODE 0: h_in -> dst0,dst1 words 0..63   MODE 1: s_out -> dst0 words 64..95
// MODE 2: floats -> fout
template <int SRCW, int MODE>
__global__ __launch_bounds__(256) void ram_layer_t(const uint32_t* __restrict__ src,
                                                   const int* __restrict__ conn,
                                                   const uint32_t* __restrict__ memp,
                                                   uint32_t* __restrict__ dst0,
                                                   uint32_t* __restrict__ dst1,
                                                   float* __restrict__ fout) {
    constexpr int LSTR = SRCW + 1;           // odd -> conflict-free column reads
    __shared__ uint32_t lds[64 * LSTR];
    const int tid = threadIdx.x;
    const int b0 = blockIdx.y * 64;
    {
        const uint4* g = (const uint4*)(src + (long)b0 * SRCW);
        constexpr int NQ = 64 * SRCW / 4;
#pragma unroll
        for (int i = tid; i < NQ; i += 256) {
            uint4 v = g[i];
            int r = i / (SRCW / 4);
            int w = (i - r * (SRCW / 4)) * 4;
            uint32_t* p = &lds[r * LSTR + w];
            p[0] = v.x; p[1] = v.y; p[2] = v.z; p[3] = v.w;
        }
    }
    __syncthreads();
    const int lane = tid & 63;
    const int wave = __builtin_amdgcn_readfirstlane(tid >> 6);
    const int nw0 = blockIdx.x * 64 + wave * 16;
    const long b = b0 + lane;
    const uint32_t* row = lds + lane * LSTR;
    uint32_t acc = 0;
#pragma unroll 2
    for (int j = 0; j < 16; ++j) {
        const int n = nw0 + j;
        const int* cp = conn + n * KBITS;
        uint32_t addr = 0;
#pragma unroll
        for (int k = 0; k < KBITS; ++k) {
            int idx = cp[k];
            int wd, sh;
            if (SRCW == 128) {               // bits1 is ballot layout
                wd = ((idx >> 5) & ~7) | ((idx & 3) << 1) | ((idx >> 7) & 1);
                sh = (idx >> 2) & 31;
            } else {                         // SROW buffers are linear layout
                wd = idx >> 5;
                sh = idx & 31;
            }
            addr = (addr << 1) | ((row[wd] >> sh) & 1u);
        }
        // mem tables are ballot layout: remap bit address -> (word, shift)
        uint32_t mw = ((addr >> 5) & ~7u) | ((addr & 3u) << 1) | ((addr >> 7) & 1u);
        uint32_t bit = (memp[(long)n * MW + mw] >> ((addr >> 2) & 31u)) & 1u;
        if (MODE == 2) fout[b * N_OUT + n] = (float)bit;
        else           acc |= bit << j;
    }
    if (MODE != 2) {
        const int woff = (MODE == 0 ? 0 : 64) + (nw0 >> 5);
        const int half = (nw0 >> 4) & 1;
        ((ushort*)(dst0 + b * SROW + woff))[half] = (ushort)acc;
        if (MODE == 0)
            ((ushort*)(dst1 + b * SROW + woff))[half] = (ushort)acc;
    }
}

// ---------------------------------------------------------------------------
extern "C" void kernel_launch(void* const* d_in, const int* in_sizes, int n_in,
                              void* d_out, int out_size, void* d_ws, size_t ws_size,
                              hipStream_t stream) {
    const int*   input_bits = (const int*)d_in[0];
    const int*   state_bits = (const int*)d_in[1];
    const int*   in_conn    = (const int*)d_in[2];
    const float* in_mem     = (const float*)d_in[3];
    const int*   st_conn    = (const int*)d_in[4];
    const float* st_mem     = (const float*)d_in[5];
    const int*   out_conn   = (const int*)d_in[6];
    const float* out_mem    = (const float*)d_in[7];
    float*       out        = (float*)d_out;

    // Workspace layout (all 256B-aligned):
    //   bits1 : [B][128] u32  = 1 MB   (packed input_bits, ballot layout)
    //   buf_s : [B][96]  u32  = 768 KB (s_inp bits: h_in | state, linear)
    //   buf_o : [B][96]  u32  = 768 KB (o_inp bits: h_in | s_out, linear)
    //   im_p  : [2048][512]   = 4 MB   (ballot layout)
    //   sm_p  : [1024][512]   = 2 MB   (ballot layout)
    //   om_p  : [1024][512]   = 2 MB   (ballot layout)
    char* ws = (char*)d_ws;
    uint32_t* bits1 = (uint32_t*)(ws);
    uint32_t* buf_s = (uint32_t*)(ws + 1048576);
    uint32_t* buf_o = (uint32_t*)(ws + 1048576 + 786432);
    uint32_t* im_p  = (uint32_t*)(ws + 1048576 + 2 * 786432);
    uint32_t* sm_p  = (uint32_t*)(ws + 1048576 + 2 * 786432 + 4194304);
    uint32_t* om_p  = (uint32_t*)(ws + 1048576 + 2 * 786432 + 4194304 + 2097152);

    // One packing pass (deep-batched loads), then the three RAM layers.
    pack_all<<<2048, 256, 0, stream>>>(in_mem, st_mem, out_mem,
                                       input_bits, state_bits,
                                       im_p, sm_p, om_p, bits1, buf_s);
    ram_layer_t<128, 0><<<dim3(N_IN / 64, BATCH / 64), 256, 0, stream>>>(
        bits1, in_conn, im_p, buf_s, buf_o, nullptr);
    ram_layer_t<SROW, 1><<<dim3(N_ST / 64, BATCH / 64), 256, 0, stream>>>(
        buf_s, st_conn, sm_p, buf_o, nullptr, nullptr);
    ram_layer_t<SROW, 2><<<dim3(N_OUT / 64, BATCH / 64), 256, 0, stream>>>(
        buf_o, out_conn, om_p, nullptr, nullptr, out);
}

// Round 6
// 357.620 us; speedup vs baseline: 2.0034x; 1.0472x over previous
//
#include <hip/hip_runtime.h>
#include <stdint.h>

// Problem constants (from reference)
#define BATCH   2048
#define IN_BITS 4096
#define N_IN    2048
#define N_ST    1024
#define N_OUT   1024
#define KBITS   14
#define MROW    16384  // 2^14 floats per mem row (UNPACKED — gathered directly)
#define SROW    96     // s_inp/o_inp packed row words: 3072 bits

#define GS  524288     // grid: 2048 blocks * 256 threads

typedef float f32x4 __attribute__((ext_vector_type(4)));
typedef int   i32x4 __attribute__((ext_vector_type(4)));

// ---------------------------------------------------------------------------
// R6 design note: R0-R5 pinned every streaming-pack variant of the 256 MB mem
// tables at 2-3 TB/s (one-shot, grid-stride, fused, reg-batched; VGPR 8->40)
// — mechanism never identified from available counters. This version DELETES
// that work: ram layers gather directly from the float tables
// (mem[n*16384+addr] == 1.0f). Same HBM bytes (~230 vs 268 MB: 2048 draws on
// a 64KB row touch ~880/1024 lines), zero pack stream, one fewer kernel
// boundary, and the bytes move inside gather kernels with 16 independent
// lookups/thread to hide latency. Only input/state still get bit-packed
// (40 MB) so address bits come from a 32 KB LDS row.
// ---------------------------------------------------------------------------

// Ballot-layout emit for input bits: from a loaded int4, form 4 ballots,
// lanes 0..7 store the chunk's 8 u32 words. Consumer remap for bit addr a:
//   word = ((a>>5)&~7) | ((a&3)<<1) | ((a>>7)&1);  shift = (a>>2)&31
__device__ __forceinline__ void emit1i(uint32_t* __restrict__ d, long i,
                                       int lane, i32x4 v) {
    unsigned long long b0 = __ballot(v[0] == 1);
    unsigned long long b1 = __ballot(v[1] == 1);
    unsigned long long b2 = __ballot(v[2] == 1);
    unsigned long long b3 = __ballot(v[3] == 1);
    if (lane < 8) {
        unsigned long long bj = (lane & 4) ? ((lane & 2) ? b3 : b2)
                                           : ((lane & 2) ? b1 : b0);
        uint32_t w = (lane & 1) ? (uint32_t)(bj >> 32) : (uint32_t)bj;
        d[((i >> 6) << 3) + lane] = w;
    }
}

// Pack input_bits (ballot layout -> bits1) and state_bits (linear layout ->
// buf_s words 64..95). 40 MB total read; loads batched up front.
__global__ __launch_bounds__(256) void pack_in_st(const int* __restrict__ ib,
                                                  const int* __restrict__ sb,
                                                  uint32_t* __restrict__ bits1,
                                                  uint32_t* __restrict__ buf_s) {
    const long t = blockIdx.x * 256 + threadIdx.x;   // [0, GS)
    const int lane = threadIdx.x & 63;
    i32x4 wi[4];
#pragma unroll
    for (int u = 0; u < 4; ++u) wi[u] = ((const i32x4*)ib)[(long)u * GS + t];
    i32x4 wst = ((const i32x4*)sb)[t];
#pragma unroll
    for (int u = 0; u < 4; ++u) emit1i(bits1, (long)u * GS + t, lane, wi[u]);
    // state -> buf_s words 64..95, LINEAR layout (matches SROW consumers)
    uint32_t nib = (uint32_t)(wst[0] == 1) | ((uint32_t)(wst[1] == 1) << 1) |
                   ((uint32_t)(wst[2] == 1) << 2) | ((uint32_t)(wst[3] == 1) << 3);
    uint32_t w = nib << (4 * (lane & 7));
    w |= __shfl_xor(w, 1, 64);
    w |= __shfl_xor(w, 2, 64);
    w |= __shfl_xor(w, 4, 64);
    if ((lane & 7) == 0) {
        long g = t >> 3;          // global word index
        buf_s[(g >> 5) * SROW + 64 + (int)(g & 31)] = w;
    }
}

// ---------------------------------------------------------------------------
// TRANSPOSED RAM layer with DIRECT float-table gather.
// lane = batch (64/block), wave = 16-neuron group. conn wave-uniform (scalar
// loads); LDS reads via odd stride -> 2 lanes/bank (free); gather hits one
// 64KB float row per wave-instr (x = neuron-group -> all batch-groups of a
// group land on one XCD: linear = x + y*32, 32%8==0 -> XCD = x%8).
// MODE 0: h_in -> dst0,dst1 words 0..63   MODE 1: s_out -> dst0 words 64..95
// MODE 2: 16 bits/lane -> 4x float4 stores (64B line per lane)
template <int SRCW, int MODE>
__global__ __launch_bounds__(256) void ram_layer_f(const uint32_t* __restrict__ src,
                                                   const int* __restrict__ conn,
                                                   const float* __restrict__ memf,
                                                   uint32_t* __restrict__ dst0,
                                                   uint32_t* __restrict__ dst1,
                                                   float* __restrict__ fout) {
    constexpr int LSTR = SRCW + 1;           // odd -> conflict-free column reads
    __shared__ uint32_t lds[64 * LSTR];
    const int tid = threadIdx.x;
    const int b0 = blockIdx.y * 64;
    {
        const uint4* g = (const uint4*)(src + (long)b0 * SRCW);
        constexpr int NQ = 64 * SRCW / 4;
#pragma unroll
        for (int i = tid; i < NQ; i += 256) {
            uint4 v = g[i];
            int r = i / (SRCW / 4);
            int w = (i - r * (SRCW / 4)) * 4;
            uint32_t* p = &lds[r * LSTR + w];
            p[0] = v.x; p[1] = v.y; p[2] = v.z; p[3] = v.w;
        }
    }
    __syncthreads();
    const int lane = tid & 63;
    const int wave = __builtin_amdgcn_readfirstlane(tid >> 6);
    const int nw0 = blockIdx.x * 64 + wave * 16;
    const long b = b0 + lane;
    const uint32_t* row = lds + lane * LSTR;
    uint32_t acc = 0;
#pragma unroll 4
    for (int j = 0; j < 16; ++j) {
        const int n = nw0 + j;
        const int* cp = conn + n * KBITS;    // wave-uniform -> scalar loads
        uint32_t addr = 0;
#pragma unroll
        for (int k = 0; k < KBITS; ++k) {
            int idx = cp[k];
            int wd, sh;
            if (SRCW == 128) {               // bits1 is ballot layout
                wd = ((idx >> 5) & ~7) | ((idx & 3) << 1) | ((idx >> 7) & 1);
                sh = (idx >> 2) & 31;
            } else {                         // SROW buffers are linear layout
                wd = idx >> 5;
                sh = idx & 31;
            }
            addr = (addr << 1) | ((row[wd] >> sh) & 1u);
        }
        // Direct gather from the float table (TRUE == 1.0f).
        float v = memf[(long)n * MROW + addr];
        acc |= ((v == 1.0f) ? 1u : 0u) << j;
    }
    if (MODE == 2) {
        float* op = fout + b * N_OUT + nw0;  // 16 consecutive floats = 64B
#pragma unroll
        for (int q = 0; q < 4; ++q) {
            f32x4 f;
#pragma unroll
            for (int e = 0; e < 4; ++e) f[e] = (float)((acc >> (q * 4 + e)) & 1u);
            ((f32x4*)op)[q] = f;
        }
    } else {
        const int woff = (MODE == 0 ? 0 : 64) + (nw0 >> 5);
        const int half = (nw0 >> 4) & 1;
        ((ushort*)(dst0 + b * SROW + woff))[half] = (ushort)acc;
        if (MODE == 0)
            ((ushort*)(dst1 + b * SROW + woff))[half] = (ushort)acc;
    }
}

// ---------------------------------------------------------------------------
extern "C" void kernel_launch(void* const* d_in, const int* in_sizes, int n_in,
                              void* d_out, int out_size, void* d_ws, size_t ws_size,
                              hipStream_t stream) {
    const int*   input_bits = (const int*)d_in[0];
    const int*   state_bits = (const int*)d_in[1];
    const int*   in_conn    = (const int*)d_in[2];
    const float* in_mem     = (const float*)d_in[3];
    const int*   st_conn    = (const int*)d_in[4];
    const float* st_mem     = (const float*)d_in[5];
    const int*   out_conn   = (const int*)d_in[6];
    const float* out_mem    = (const float*)d_in[7];
    float*       out        = (float*)d_out;

    // Workspace layout (all 256B-aligned):
    //   bits1 : [B][128] u32  = 1 MB   (packed input_bits, ballot layout)
    //   buf_s : [B][96]  u32  = 768 KB (s_inp bits: h_in | state, linear)
    //   buf_o : [B][96]  u32  = 768 KB (o_inp bits: h_in | s_out, linear)
    //   (mem tables are NOT packed — gathered directly as floats)
    char* ws = (char*)d_ws;
    uint32_t* bits1 = (uint32_t*)(ws);
    uint32_t* buf_s = (uint32_t*)(ws + 1048576);
    uint32_t* buf_o = (uint32_t*)(ws + 1048576 + 786432);

    pack_in_st<<<2048, 256, 0, stream>>>(input_bits, state_bits, bits1, buf_s);
    // Layer 1: input_bits -> h_in (into both buf_s and buf_o, words 0..63)
    ram_layer_f<128, 0><<<dim3(N_IN / 64, BATCH / 64), 256, 0, stream>>>(
        bits1, in_conn, in_mem, buf_s, buf_o, nullptr);
    // Layer 2: s_inp -> s_out (into buf_o words 64..95)
    ram_layer_f<SROW, 1><<<dim3(N_ST / 64, BATCH / 64), 256, 0, stream>>>(
        buf_s, st_conn, st_mem, buf_o, nullptr, nullptr);
    // Layer 3: o_inp -> output floats
    ram_layer_f<SROW, 2><<<dim3(N_OUT / 64, BATCH / 64), 256, 0, stream>>>(
        buf_o, out_conn, out_mem, nullptr, nullptr, out);
}